// Round 3
// baseline (426.098 us; speedup 1.0000x reference)
//
#include <hip/hip_runtime.h>

// FlowWarp via MFMA. Per level:
//   warped = bilinear_warp(xp, +fl); x = [xc(64) | warped(64) | fl(2)] (130ch)
//   out[p][f] = sum_c x[c]*dw[c]*pw[c][f] + bias[f]
// R3: per-pixel 130x64 matvec as bf16 MFMA 16x16x32; weights prepped into
//   B-fragment order in d_ws; phase1 gather->LDS bf16, phase2 MFMA.
// R4: 32KB LDS + XOR swizzle + launch_bounds(256,5): occ 27->37%, conflicts->0,
//   but dur 178->190us: WRITE_SIZE 98->135MB (partial-line evictions: epilogue
//   wrote each 256B out row as 16 scattered 4B stores) + write-allocate
//   re-fetch (+35MB FETCH). Occupancy win eaten by L2 write thrash.
// R5: attack the thrash + decouple waves:
//   1. B-col permutation col=4*m16+nt -> epilogue emits ONE 16B nt-store
//      per row (full lines, no write-allocate, out bypasses L2).
//   2. drop __syncthreads: wave w's MFMA rows == wave w's own gathered pixels
//      -> intra-wave dep only; s_waitcnt lgkmcnt(0) suffices. Waves flow
//      gather->MFMA independently (mutual latency hiding).
//   3. fl epilogue values via __shfl from phase-1 regs (no global re-read);
//      one-ahead xc prefetch across mt; nontemporal xc loads (read-once
//      stream, keep L2 for xp gather reuse).
// R5b (this): compile fix only — __builtin_nontemporal_* requires native
//   vector types; HIP float4 is a class. Use ext_vector f32x4 throughout
//   the nontemporal paths.

typedef __attribute__((ext_vector_type(8))) short bf16x8;
typedef __attribute__((ext_vector_type(4))) float f32x4;

#define WS_LVL_STRIDE 17408  // 16384 frag bytes + 768 table bytes, 256-align

__device__ inline unsigned rne_bf16_bits(float f) {
  unsigned u = __builtin_bit_cast(unsigned, f);
  u += 0x7fffu + ((u >> 16) & 1u);
  return u >> 16;
}
__device__ inline int pack_bf16x2(float a, float b) {
  return (int)(rne_bf16_bits(a) | (rne_bf16_bits(b) << 16));
}

struct LevelArgs {
  const float* __restrict__ xc;
  const float* __restrict__ xp;
  const float* __restrict__ fl;
  float* __restrict__ out;
  const char* __restrict__ wsl;  // frag[16KB] + tab[768B]
  int H, W, npix, block_start;
};
struct KArgs { LevelArgs lv[6]; int total_blocks; };

struct PrepLevel {
  const float* __restrict__ dw;
  const float* __restrict__ pw;
  const float* __restrict__ bias;
  char* __restrict__ wsl;
};
struct PrepArgs { PrepLevel lv[6]; };

// ---- prep: fold dw into pw, pack B-fragments.
// Lane l of frag (kt,nt) holds B[k = kt*32 + ((l>>4)&3)*8 + j][col(l,nt)]
// with col = 4*(l&15) + nt  (R5: column permutation so the epilogue's 4
// accumulators per lane are CONSECUTIVE output cols -> 16B store).
__global__ void prep_kernel(PrepArgs pa) {
  const PrepLevel P = pa.lv[blockIdx.x];
  int4* __restrict__ frag = (int4*)P.wsl;
  for (int e = (int)threadIdx.x; e < 1024; e += 256) {
    const int kt = e >> 8;            // k-tile 0..3 (k = kt*32 + ...)
    const int nt = (e >> 6) & 3;      // n-tile 0..3
    const int lane = e & 63;
    const int n = 4 * (lane & 15) + nt;   // R5 permuted column
    const int kb = kt * 32 + ((lane >> 4) & 3) * 8;
    int v[4];
#pragma unroll
    for (int jj = 0; jj < 4; ++jj) {
      const int k0 = kb + jj * 2;
      const float w0 = P.dw[k0] * P.pw[(size_t)k0 * 64 + n];
      const float w1 = P.dw[k0 + 1] * P.pw[(size_t)(k0 + 1) * 64 + n];
      v[jj] = pack_bf16x2(w0, w1);
    }
    frag[e] = make_int4(v[0], v[1], v[2], v[3]);
  }
  float* __restrict__ tab = (float*)(P.wsl + 16384);
  if (threadIdx.x < 64) {
    const int f = (int)threadIdx.x;
    tab[f] = P.bias[f];
    tab[64 + f] = P.dw[128] * P.pw[128 * 64 + f];
    tab[128 + f] = P.dw[129] * P.pw[129 * 64 + f];
  }
}

// LDS: 256 rows x 128B (64ch bf16), XOR-swizzled; 5 blocks/CU = 160KB exact.
// Swizzle: byte offset within row ^= (row&7)<<4 — bijective per 8-row
// stripe, all accesses 16B-aligned; bank conflicts measured 0.
#define SWZ(r, o) \
  ((((unsigned)(r)) << 7) | (((unsigned)(o)) ^ ((((unsigned)(r)) & 7u) << 4)))

__global__ __launch_bounds__(256, 5) void flowwarp_mfma(KArgs ka) {
  __shared__ __align__(16) char lds_raw[256 * 128];

  const int nb = ka.total_blocks;
  const int chunk = (nb + 7) >> 3;
  const int bp = (int)blockIdx.x;
  const int b = (bp & 7) * chunk + (bp >> 3);   // XCD-slab swizzle
  if (b >= nb) return;

  int Lr = 0;
#pragma unroll
  for (int i = 1; i < 6; ++i) Lr = (b >= ka.lv[i].block_start) ? i : Lr;
  const int L = __builtin_amdgcn_readfirstlane(Lr);
  const LevelArgs A = ka.lv[L];

  const int q = (int)threadIdx.x;
  const int p0 = (b - A.block_start) * 256;
  const int W = A.W, H = A.H;

  float fl0, fl1;  // this thread's pixel flow — reused by epilogue via shfl

  // ================= phase 1: bilinear gather -> LDS (bf16) =================
  {
    int p = p0 + q;
    if (p > A.npix - 1) p = A.npix - 1;   // tail blocks: clamp (rows unused)
    const int x = p % W;
    const int t = p / W;
    const int y = t % H;
    const int n = t / H;

    fl0 = A.fl[2 * (size_t)p];
    fl1 = A.fl[2 * (size_t)p + 1];

    const float qy = (float)y + fl0;
    const float qx = (float)x + fl1;
    const float fy = fminf(fmaxf(floorf(qy), 0.0f), (float)(H - 2));
    const float fx = fminf(fmaxf(floorf(qx), 0.0f), (float)(W - 2));
    const int y0 = (int)fy, x0 = (int)fx;
    const float ay = fminf(fmaxf(qy - fy, 0.0f), 1.0f);
    const float ax = fminf(fmaxf(qx - fx, 0.0f), 1.0f);

    const float* __restrict__ base =
        A.xp + ((size_t)((n * H + y0) * W + x0)) * 64;
    const int W64 = W * 64;
    const f32x4* __restrict__ tl4 = (const f32x4*)base;
    const f32x4* __restrict__ tr4 = (const f32x4*)(base + 64);
    const f32x4* __restrict__ bl4 = (const f32x4*)(base + W64);
    const f32x4* __restrict__ br4 = (const f32x4*)(base + W64 + 64);

#pragma unroll 1
    for (int bq = 0; bq < 4; ++bq) {   // 4 bursts x 16 ch: full-line consume
      f32x4 rtl[4], rtr[4], rbl[4], rbr[4];
#pragma unroll
      for (int i = 0; i < 4; ++i) {
        rtl[i] = tl4[bq * 4 + i];
        rtr[i] = tr4[bq * 4 + i];
        rbl[i] = bl4[bq * 4 + i];
        rbr[i] = br4[bq * 4 + i];
      }
      int v[8];
#pragma unroll
      for (int i = 0; i < 4; ++i) {
        float wv[4];
#pragma unroll
        for (int j = 0; j < 4; ++j) {
          const float top = fmaf(rtr[i][j] - rtl[i][j], ax, rtl[i][j]);
          const float bot = fmaf(rbr[i][j] - rbl[i][j], ax, rbl[i][j]);
          wv[j] = fmaf(bot - top, ay, top);
        }
        v[i * 2] = pack_bf16x2(wv[0], wv[1]);
        v[i * 2 + 1] = pack_bf16x2(wv[2], wv[3]);
      }
      *(int4*)(lds_raw + SWZ(q, bq * 32)) = make_int4(v[0], v[1], v[2], v[3]);
      *(int4*)(lds_raw + SWZ(q, bq * 32 + 16)) =
          make_int4(v[4], v[5], v[6], v[7]);
    }
  }
  // R5: no __syncthreads — each wave's phase-2 rows are its own 64 threads'
  // gathered pixels. Only need this wave's LDS writes complete.
  asm volatile("s_waitcnt lgkmcnt(0)" ::: "memory");

  // ================= phase 2: MFMA 64pix x 64f per wave =================
  const int lane = q & 63;
  const int w = q >> 6;
  const int m16 = lane & 15;
  const int q4l = lane >> 4;

  // B-fragments: 4 ktiles x 4 ntiles, 16B/lane each
  const int4* __restrict__ bfr = (const int4*)A.wsl;
  bf16x8 Bf[4][4];
#pragma unroll
  for (int kt = 0; kt < 4; ++kt)
#pragma unroll
    for (int nt = 0; nt < 4; ++nt)
      Bf[kt][nt] = __builtin_bit_cast(bf16x8, bfr[(kt * 4 + nt) * 64 + lane]);

  // epilogue tables: this lane's 4 consecutive cols 4*m16..4*m16+3
  const float* __restrict__ tab = (const float*)(A.wsl + 16384);
  const f32x4 bvv  = *(const f32x4*)(tab + 4 * m16);
  const f32x4 t0vv = *(const f32x4*)(tab + 64 + 4 * m16);
  const f32x4 t1vv = *(const f32x4*)(tab + 128 + 4 * m16);

  // one-ahead xc prefetch (nontemporal: read-once stream, spare L2 for xp)
  const int npix1 = A.npix - 1;
  int pm = p0 + w * 64 + m16;
  if (pm > npix1) pm = npix1;
  const float* __restrict__ xcp = A.xc + (size_t)pm * 64 + q4l * 8;
  f32x4 na0 = __builtin_nontemporal_load((const f32x4*)xcp);
  f32x4 na1 = __builtin_nontemporal_load((const f32x4*)(xcp + 4));
  f32x4 na2 = __builtin_nontemporal_load((const f32x4*)(xcp + 32));
  f32x4 na3 = __builtin_nontemporal_load((const f32x4*)(xcp + 36));

#pragma unroll 1
  for (int mt = 0; mt < 4; ++mt) {
    const int lrow = w * 64 + mt * 16;
    const f32x4 a0 = na0, a1 = na1, a2 = na2, a3 = na3;
    if (mt < 3) {
      int pn = p0 + lrow + 16 + m16;
      if (pn > npix1) pn = npix1;
      const float* __restrict__ xn = A.xc + (size_t)pn * 64 + q4l * 8;
      na0 = __builtin_nontemporal_load((const f32x4*)xn);
      na1 = __builtin_nontemporal_load((const f32x4*)(xn + 4));
      na2 = __builtin_nontemporal_load((const f32x4*)(xn + 32));
      na3 = __builtin_nontemporal_load((const f32x4*)(xn + 36));
    }
    int av[8];
    av[0] = pack_bf16x2(a0[0], a0[1]); av[1] = pack_bf16x2(a0[2], a0[3]);
    av[2] = pack_bf16x2(a1[0], a1[1]); av[3] = pack_bf16x2(a1[2], a1[3]);
    av[4] = pack_bf16x2(a2[0], a2[1]); av[5] = pack_bf16x2(a2[2], a2[3]);
    av[6] = pack_bf16x2(a3[0], a3[1]); av[7] = pack_bf16x2(a3[2], a3[3]);
    const bf16x8 A0 = __builtin_bit_cast(bf16x8, make_int4(av[0], av[1], av[2], av[3]));
    const bf16x8 A1 = __builtin_bit_cast(bf16x8, make_int4(av[4], av[5], av[6], av[7]));
    // A-frags, warped (k-tiles 2,3) from LDS (swizzled, own-wave rows)
    const int rr = lrow + m16;
    const bf16x8 A2 = __builtin_bit_cast(
        bf16x8, *(const int4*)(lds_raw + SWZ(rr, q4l * 16)));
    const bf16x8 A3 = __builtin_bit_cast(
        bf16x8, *(const int4*)(lds_raw + SWZ(rr, 64 + q4l * 16)));

    f32x4 acc[4] = {{0.f, 0.f, 0.f, 0.f}, {0.f, 0.f, 0.f, 0.f},
                    {0.f, 0.f, 0.f, 0.f}, {0.f, 0.f, 0.f, 0.f}};
#pragma unroll
    for (int nt = 0; nt < 4; ++nt) {
      acc[nt] = __builtin_amdgcn_mfma_f32_16x16x32_bf16(A0, Bf[0][nt], acc[nt], 0, 0, 0);
      acc[nt] = __builtin_amdgcn_mfma_f32_16x16x32_bf16(A1, Bf[1][nt], acc[nt], 0, 0, 0);
      acc[nt] = __builtin_amdgcn_mfma_f32_16x16x32_bf16(A2, Bf[2][nt], acc[nt], 0, 0, 0);
      acc[nt] = __builtin_amdgcn_mfma_f32_16x16x32_bf16(A3, Bf[3][nt], acc[nt], 0, 0, 0);
    }

    // epilogue: D row r=q4l*4+i; this lane's cols are 4*m16..4*m16+3
    // (acc[nt] -> col 4*m16+nt). fl terms exact fp32, fetched by shfl from
    // the wave-mate that gathered that pixel. One full 16B nt-store/row.
#pragma unroll
    for (int i = 0; i < 4; ++i) {
      const int srcl = mt * 16 + q4l * 4 + i;
      const float f0i = __shfl(fl0, srcl);
      const float f1i = __shfl(fl1, srcl);
      const int prow = p0 + lrow + q4l * 4 + i;
      if (prow < A.npix) {
        f32x4 o;
        o[0] = acc[0][i] + bvv[0] + f0i * t0vv[0] + f1i * t1vv[0];
        o[1] = acc[1][i] + bvv[1] + f0i * t0vv[1] + f1i * t1vv[1];
        o[2] = acc[2][i] + bvv[2] + f0i * t0vv[2] + f1i * t1vv[2];
        o[3] = acc[3][i] + bvv[3] + f0i * t1vv[3] * 0.0f + f1i * t1vv[3] +
               f0i * t0vv[3];
        __builtin_nontemporal_store(
            o, (f32x4*)(A.out + (size_t)prow * 64 + 4 * m16));
      }
    }
  }
}

extern "C" void kernel_launch(void* const* d_in, const int* in_sizes, int n_in,
                              void* d_out, int out_size, void* d_ws, size_t ws_size,
                              hipStream_t stream) {
  static const int HS[6] = {192, 96, 48, 24, 12, 6};
  static const int WS[6] = {384, 192, 96, 48, 24, 12};
  PrepArgs pa;
  KArgs ka;
  int bstart = 0;
  size_t ooff = 0;
  for (int i = 0; i < 6; ++i) {
    char* wsl = (char*)d_ws + (size_t)i * WS_LVL_STRIDE;
    pa.lv[i].dw   = (const float*)d_in[6 * i + 3];
    pa.lv[i].pw   = (const float*)d_in[6 * i + 4];
    pa.lv[i].bias = (const float*)d_in[6 * i + 5];
    pa.lv[i].wsl  = wsl;
    ka.lv[i].xc  = (const float*)d_in[6 * i + 0];
    ka.lv[i].xp  = (const float*)d_in[6 * i + 1];
    ka.lv[i].fl  = (const float*)d_in[6 * i + 2];
    ka.lv[i].out = (float*)d_out + ooff;
    ka.lv[i].wsl = wsl;
    const int npix = 4 * HS[i] * WS[i];
    ka.lv[i].H = HS[i];
    ka.lv[i].W = WS[i];
    ka.lv[i].npix = npix;
    ka.lv[i].block_start = bstart;
    bstart += (npix + 255) / 256;
    ooff += (size_t)npix * 64;
  }
  ka.total_blocks = bstart;
  prep_kernel<<<dim3(6), dim3(256), 0, stream>>>(pa);
  const int chunk = (bstart + 7) >> 3;
  flowwarp_mfma<<<dim3(chunk * 8), dim3(256), 0, stream>>>(ka);
}

// Round 4
// 375.440 us; speedup vs baseline: 1.1349x; 1.1349x over previous
//
#include <hip/hip_runtime.h>

// FlowWarp via MFMA. Per level:
//   warped = bilinear_warp(xp, +fl); x = [xc(64) | warped(64) | fl(2)] (130ch)
//   out[p][f] = sum_c x[c]*dw[c]*pw[c][f] + bias[f]
// R3: per-pixel 130x64 matvec as bf16 MFMA 16x16x32; weights prepped into
//   B-fragment order in d_ws; phase1 gather->LDS bf16, phase2 MFMA.
// R4: 32KB LDS + XOR swizzle + 5 blocks/CU: occ 27->37%, conflicts 0, but
//   dur 178->190us and FETCH 109->172MB: more waves deepened the vec-mem
//   queues; gather is TRANSACTION-bound, not latency-bound.
// R5: B-col permutation (full-line f32x4 stores), no __syncthreads, nt hints.
//   nt hints REGRESSED (FETCH +13MB: nt-loads kill L2 reuse across the 4
//   split loads of each xc line; WRITE +18MB: nt-stores bypass L2 write
//   combining). dur 195us.
// R6 (this):
//   1. LANE-COOPERATIVE GATHER: 16 groups x 4 lanes; each group owns one
//      pixel per round (params via __shfl), 4 lanes read consecutive 16B of
//      one 64B corner line -> each instr = 16 coalesced lines = 16 txns
//      (was 64). Gather txns/wave 4096 -> 1024. Same bytes, same VALU.
//   2. revert nt hints (measured regression): regular loads/stores, L2
//      write-back reassembles full 256B out rows (keep R5's B-col permute
//      + single 16B store per row).

typedef __attribute__((ext_vector_type(8))) short bf16x8;
typedef __attribute__((ext_vector_type(4))) float f32x4;

#define WS_LVL_STRIDE 17408  // 16384 frag bytes + 768 table bytes, 256-align

__device__ inline unsigned rne_bf16_bits(float f) {
  unsigned u = __builtin_bit_cast(unsigned, f);
  u += 0x7fffu + ((u >> 16) & 1u);
  return u >> 16;
}
__device__ inline int pack_bf16x2(float a, float b) {
  return (int)(rne_bf16_bits(a) | (rne_bf16_bits(b) << 16));
}

struct LevelArgs {
  const float* __restrict__ xc;
  const float* __restrict__ xp;
  const float* __restrict__ fl;
  float* __restrict__ out;
  const char* __restrict__ wsl;  // frag[16KB] + tab[768B]
  int H, W, npix, block_start;
};
struct KArgs { LevelArgs lv[6]; int total_blocks; };

struct PrepLevel {
  const float* __restrict__ dw;
  const float* __restrict__ pw;
  const float* __restrict__ bias;
  char* __restrict__ wsl;
};
struct PrepArgs { PrepLevel lv[6]; };

// ---- prep: fold dw into pw, pack B-fragments.
// Lane l of frag (kt,nt) holds B[k = kt*32 + ((l>>4)&3)*8 + j][col(l,nt)]
// with col = 4*(l&15) + nt  (R5 column permutation: the epilogue's 4
// accumulators per lane are CONSECUTIVE output cols -> one 16B store).
__global__ void prep_kernel(PrepArgs pa) {
  const PrepLevel P = pa.lv[blockIdx.x];
  int4* __restrict__ frag = (int4*)P.wsl;
  for (int e = (int)threadIdx.x; e < 1024; e += 256) {
    const int kt = e >> 8;            // k-tile 0..3 (k = kt*32 + ...)
    const int nt = (e >> 6) & 3;      // n-tile 0..3
    const int lane = e & 63;
    const int n = 4 * (lane & 15) + nt;   // permuted column
    const int kb = kt * 32 + ((lane >> 4) & 3) * 8;
    int v[4];
#pragma unroll
    for (int jj = 0; jj < 4; ++jj) {
      const int k0 = kb + jj * 2;
      const float w0 = P.dw[k0] * P.pw[(size_t)k0 * 64 + n];
      const float w1 = P.dw[k0 + 1] * P.pw[(size_t)(k0 + 1) * 64 + n];
      v[jj] = pack_bf16x2(w0, w1);
    }
    frag[e] = make_int4(v[0], v[1], v[2], v[3]);
  }
  float* __restrict__ tab = (float*)(P.wsl + 16384);
  if (threadIdx.x < 64) {
    const int f = (int)threadIdx.x;
    tab[f] = P.bias[f];
    tab[64 + f] = P.dw[128] * P.pw[128 * 64 + f];
    tab[128 + f] = P.dw[129] * P.pw[129 * 64 + f];
  }
}

// LDS: 256 rows x 128B (64ch bf16), XOR-swizzled; 5 blocks/CU = 160KB exact.
// Swizzle: byte offset within row ^= (row&7)<<4 — bijective per 8-row
// stripe; flips only bit 4, so 8B/16B alignment is preserved on both the
// phase-1 8B writes and phase-2 16B reads. Bank conflicts measured 0 (R4).
#define SWZ(r, o) \
  ((((unsigned)(r)) << 7) | (((unsigned)(o)) ^ ((((unsigned)(r)) & 7u) << 4)))

__global__ __launch_bounds__(256, 5) void flowwarp_mfma(KArgs ka) {
  __shared__ __align__(16) char lds_raw[256 * 128];

  const int nb = ka.total_blocks;
  const int chunk = (nb + 7) >> 3;
  const int bp = (int)blockIdx.x;
  const int b = (bp & 7) * chunk + (bp >> 3);   // XCD-slab swizzle
  if (b >= nb) return;

  int Lr = 0;
#pragma unroll
  for (int i = 1; i < 6; ++i) Lr = (b >= ka.lv[i].block_start) ? i : Lr;
  const int L = __builtin_amdgcn_readfirstlane(Lr);
  const LevelArgs A = ka.lv[L];

  const int q = (int)threadIdx.x;
  const int p0 = (b - A.block_start) * 256;
  const int W = A.W, H = A.H;
  const int lane = q & 63;
  const int w = q >> 6;
  const int wbase = w * 64;          // this wave's first row-in-block

  float fl0, fl1;  // this thread's own-pixel flow — epilogue reads via shfl

  // ============ phase 1: cooperative bilinear gather -> LDS (bf16) ========
  {
    // per-lane own-pixel warp params
    int p = p0 + q;
    if (p > A.npix - 1) p = A.npix - 1;   // tail blocks: clamp (rows unused)
    const int x = p % W;
    const int t = p / W;
    const int y = t % H;
    const int n = t / H;

    fl0 = A.fl[2 * (size_t)p];
    fl1 = A.fl[2 * (size_t)p + 1];

    const float qy = (float)y + fl0;
    const float qx = (float)x + fl1;
    const float fy = fminf(fmaxf(floorf(qy), 0.0f), (float)(H - 2));
    const float fx = fminf(fmaxf(floorf(qx), 0.0f), (float)(W - 2));
    const int y0 = (int)fy, x0 = (int)fx;
    const float ay = fminf(fmaxf(qy - fy, 0.0f), 1.0f);
    const float ax = fminf(fmaxf(qx - fx, 0.0f), 1.0f);
    // byte offset of this pixel's top-left corner row (xp is [pix][64]f32)
    const unsigned off = (unsigned)((n * H + y0) * W + x0) * 256u;

    const char* __restrict__ xpb = (const char*)A.xp;
    const int W256 = W * 256;       // byte stride of one source row
    const int g = lane >> 2;        // group 0..15 (one pixel per round)
    const int s16 = (lane & 3) * 16;  // sub-lane byte slice within a line

#pragma unroll 1
    for (int r = 0; r < 4; ++r) {
      const int src = r * 16 + g;   // home lane of this group's pixel
      const unsigned offB = (unsigned)__shfl((int)off, src);
      const float axB = __shfl(ax, src);
      const float ayB = __shfl(ay, src);
      const int lrow = wbase + src; // LDS row == pixel-in-block index

      // two half-rounds of 2 quarters: 8 coalesced 16-txn loads in flight
#pragma unroll
      for (int h = 0; h < 2; ++h) {
        f32x4 ctl[2], ctr[2], cbl[2], cbr[2];
#pragma unroll
        for (int qd = 0; qd < 2; ++qd) {
          const int o = (h * 2 + qd) * 64 + s16;
          ctl[qd] = *(const f32x4*)(xpb + offB + o);
          ctr[qd] = *(const f32x4*)(xpb + offB + 256 + o);
          cbl[qd] = *(const f32x4*)(xpb + offB + W256 + o);
          cbr[qd] = *(const f32x4*)(xpb + offB + W256 + 256 + o);
        }
#pragma unroll
        for (int qd = 0; qd < 2; ++qd) {
          float wv[4];
#pragma unroll
          for (int j = 0; j < 4; ++j) {
            const float top = fmaf(ctr[qd][j] - ctl[qd][j], axB, ctl[qd][j]);
            const float bot = fmaf(cbr[qd][j] - cbl[qd][j], axB, cbl[qd][j]);
            wv[j] = fmaf(bot - top, ayB, top);
          }
          // lane covers channels (h*2+qd)*16 + (lane&3)*4 .. +3
          const int ob = (h * 2 + qd) * 32 + (lane & 3) * 8;
          *(int2*)(lds_raw + SWZ(lrow, ob)) =
              make_int2(pack_bf16x2(wv[0], wv[1]), pack_bf16x2(wv[2], wv[3]));
        }
      }
    }
  }
  // no __syncthreads — each wave's phase-2 rows are its own gathered pixels.
  asm volatile("s_waitcnt lgkmcnt(0)" ::: "memory");

  // ================= phase 2: MFMA 64pix x 64f per wave =================
  const int m16 = lane & 15;
  const int q4l = lane >> 4;

  // B-fragments: 4 ktiles x 4 ntiles, 16B/lane each
  const int4* __restrict__ bfr = (const int4*)A.wsl;
  bf16x8 Bf[4][4];
#pragma unroll
  for (int kt = 0; kt < 4; ++kt)
#pragma unroll
    for (int nt = 0; nt < 4; ++nt)
      Bf[kt][nt] = __builtin_bit_cast(bf16x8, bfr[(kt * 4 + nt) * 64 + lane]);

  // epilogue tables: this lane's 4 consecutive cols 4*m16..4*m16+3
  const float* __restrict__ tab = (const float*)(A.wsl + 16384);
  const f32x4 bvv  = *(const f32x4*)(tab + 4 * m16);
  const f32x4 t0vv = *(const f32x4*)(tab + 64 + 4 * m16);
  const f32x4 t1vv = *(const f32x4*)(tab + 128 + 4 * m16);

  // one-ahead xc prefetch
  const int npix1 = A.npix - 1;
  int pm = p0 + wbase + m16;
  if (pm > npix1) pm = npix1;
  const float* __restrict__ xcp = A.xc + (size_t)pm * 64 + q4l * 8;
  f32x4 na0 = *(const f32x4*)xcp;
  f32x4 na1 = *(const f32x4*)(xcp + 4);
  f32x4 na2 = *(const f32x4*)(xcp + 32);
  f32x4 na3 = *(const f32x4*)(xcp + 36);

#pragma unroll 1
  for (int mt = 0; mt < 4; ++mt) {
    const int lrow = wbase + mt * 16;
    const f32x4 a0 = na0, a1 = na1, a2 = na2, a3 = na3;
    if (mt < 3) {
      int pn = p0 + lrow + 16 + m16;
      if (pn > npix1) pn = npix1;
      const float* __restrict__ xn = A.xc + (size_t)pn * 64 + q4l * 8;
      na0 = *(const f32x4*)xn;
      na1 = *(const f32x4*)(xn + 4);
      na2 = *(const f32x4*)(xn + 32);
      na3 = *(const f32x4*)(xn + 36);
    }
    int av[8];
    av[0] = pack_bf16x2(a0[0], a0[1]); av[1] = pack_bf16x2(a0[2], a0[3]);
    av[2] = pack_bf16x2(a1[0], a1[1]); av[3] = pack_bf16x2(a1[2], a1[3]);
    av[4] = pack_bf16x2(a2[0], a2[1]); av[5] = pack_bf16x2(a2[2], a2[3]);
    av[6] = pack_bf16x2(a3[0], a3[1]); av[7] = pack_bf16x2(a3[2], a3[3]);
    const bf16x8 A0 = __builtin_bit_cast(bf16x8, make_int4(av[0], av[1], av[2], av[3]));
    const bf16x8 A1 = __builtin_bit_cast(bf16x8, make_int4(av[4], av[5], av[6], av[7]));
    // A-frags, warped (k-tiles 2,3) from LDS (swizzled, own-wave rows)
    const int rr = lrow + m16;
    const bf16x8 A2 = __builtin_bit_cast(
        bf16x8, *(const int4*)(lds_raw + SWZ(rr, q4l * 16)));
    const bf16x8 A3 = __builtin_bit_cast(
        bf16x8, *(const int4*)(lds_raw + SWZ(rr, 64 + q4l * 16)));

    f32x4 acc[4] = {{0.f, 0.f, 0.f, 0.f}, {0.f, 0.f, 0.f, 0.f},
                    {0.f, 0.f, 0.f, 0.f}, {0.f, 0.f, 0.f, 0.f}};
#pragma unroll
    for (int nt = 0; nt < 4; ++nt) {
      acc[nt] = __builtin_amdgcn_mfma_f32_16x16x32_bf16(A0, Bf[0][nt], acc[nt], 0, 0, 0);
      acc[nt] = __builtin_amdgcn_mfma_f32_16x16x32_bf16(A1, Bf[1][nt], acc[nt], 0, 0, 0);
      acc[nt] = __builtin_amdgcn_mfma_f32_16x16x32_bf16(A2, Bf[2][nt], acc[nt], 0, 0, 0);
      acc[nt] = __builtin_amdgcn_mfma_f32_16x16x32_bf16(A3, Bf[3][nt], acc[nt], 0, 0, 0);
    }

    // epilogue: D row r=q4l*4+i; this lane's cols are 4*m16..4*m16+3
    // (acc[nt] -> col 4*m16+nt). fl terms exact fp32 via shfl from the
    // wave-mate that owns that pixel. One 16B store per output row.
#pragma unroll
    for (int i = 0; i < 4; ++i) {
      const int srcl = mt * 16 + q4l * 4 + i;
      const float f0i = __shfl(fl0, srcl);
      const float f1i = __shfl(fl1, srcl);
      const int prow = p0 + lrow + q4l * 4 + i;
      if (prow < A.npix) {
        f32x4 o;
        o[0] = acc[0][i] + bvv[0] + f0i * t0vv[0] + f1i * t1vv[0];
        o[1] = acc[1][i] + bvv[1] + f0i * t0vv[1] + f1i * t1vv[1];
        o[2] = acc[2][i] + bvv[2] + f0i * t0vv[2] + f1i * t1vv[2];
        o[3] = acc[3][i] + bvv[3] + f0i * t0vv[3] + f1i * t1vv[3];
        *(f32x4*)(A.out + (size_t)prow * 64 + 4 * m16) = o;
      }
    }
  }
}

extern "C" void kernel_launch(void* const* d_in, const int* in_sizes, int n_in,
                              void* d_out, int out_size, void* d_ws, size_t ws_size,
                              hipStream_t stream) {
  static const int HS[6] = {192, 96, 48, 24, 12, 6};
  static const int WS[6] = {384, 192, 96, 48, 24, 12};
  PrepArgs pa;
  KArgs ka;
  int bstart = 0;
  size_t ooff = 0;
  for (int i = 0; i < 6; ++i) {
    char* wsl = (char*)d_ws + (size_t)i * WS_LVL_STRIDE;
    pa.lv[i].dw   = (const float*)d_in[6 * i + 3];
    pa.lv[i].pw   = (const float*)d_in[6 * i + 4];
    pa.lv[i].bias = (const float*)d_in[6 * i + 5];
    pa.lv[i].wsl  = wsl;
    ka.lv[i].xc  = (const float*)d_in[6 * i + 0];
    ka.lv[i].xp  = (const float*)d_in[6 * i + 1];
    ka.lv[i].fl  = (const float*)d_in[6 * i + 2];
    ka.lv[i].out = (float*)d_out + ooff;
    ka.lv[i].wsl = wsl;
    const int npix = 4 * HS[i] * WS[i];
    ka.lv[i].H = HS[i];
    ka.lv[i].W = WS[i];
    ka.lv[i].npix = npix;
    ka.lv[i].block_start = bstart;
    bstart += (npix + 255) / 256;
    ooff += (size_t)npix * 64;
  }
  ka.total_blocks = bstart;
  prep_kernel<<<dim3(6), dim3(256), 0, stream>>>(pa);
  const int chunk = (bstart + 7) >> 3;
  flowwarp_mfma<<<dim3(chunk * 8), dim3(256), 0, stream>>>(ka);
}